// Round 10
// baseline (346.409 us; speedup 1.0000x reference)
//
#include <hip/hip_runtime.h>
#include <hip/hip_bf16.h>
#include <stdint.h>

// out[m][n] = sum_k x[m][k] * centroids[idx[n][k]] + bias[n]
// M=8192, N=4096, K=4096. decode W->bf16, cvt x->bf16, then 256x256 MFMA GEMM.
// Round 10: r6 base, B moved out of LDS — per-wave B fragments loaded
// global->register via inline-asm global_load_dwordx4, kk-split double-buffer
// across the tile boundary. DS pipe (the measured bottleneck: ~2800 cyc/tile
// vs MFMA 2483) drops to ~1800 cyc/tile. A staging/LDS/swizzle unchanged.

typedef unsigned short u16;
typedef __attribute__((ext_vector_type(8))) short short8;   // bf16x8 (4 VGPR)
typedef __attribute__((ext_vector_type(8))) u16   u16x8;
typedef __attribute__((ext_vector_type(4))) float f32x4;
typedef __attribute__((ext_vector_type(4))) int   i32x4;

constexpr int Mdim = 8192;
constexpr int Ndim = 4096;
constexpr int Kdim = 4096;

__device__ __forceinline__ u16 f2bf(float f) {
  union { float f; uint32_t u; } v; v.f = f;
  uint32_t u = v.u;
  return (u16)((u + 0x7fffu + ((u >> 16) & 1u)) >> 16);
}

// ---------------- decode: weight_bf16[n*K + k] = bf16(cent[idx[n*K + k]]) ----
__global__ void decode_weight_kernel(const int* __restrict__ idx,
                                     const float* __restrict__ cent,
                                     u16* __restrict__ wb) {
  __shared__ u16 lut[256];
  const int t = threadIdx.x;
  if (t < 256) lut[t] = f2bf(cent[t]);
  __syncthreads();
  const size_t base = ((size_t)blockIdx.x * 256 + t) * 8;
  i32x4 i0 = *(const i32x4*)(idx + base);
  i32x4 i1 = *(const i32x4*)(idx + base + 4);
  u16x8 r;
  r[0] = lut[i0[0] & 255]; r[1] = lut[i0[1] & 255];
  r[2] = lut[i0[2] & 255]; r[3] = lut[i0[3] & 255];
  r[4] = lut[i1[0] & 255]; r[5] = lut[i1[1] & 255];
  r[6] = lut[i1[2] & 255]; r[7] = lut[i1[3] & 255];
  *(u16x8*)(wb + base) = r;
}

// ---------------- convert: x fp32 -> bf16 -----------------------------------
__global__ void cvt_x_kernel(const float* __restrict__ x, u16* __restrict__ xb) {
  const size_t base = ((size_t)blockIdx.x * 256 + threadIdx.x) * 8;
  f32x4 a = *(const f32x4*)(x + base);
  f32x4 b = *(const f32x4*)(x + base + 4);
  u16x8 r;
  r[0] = f2bf(a[0]); r[1] = f2bf(a[1]); r[2] = f2bf(a[2]); r[3] = f2bf(a[3]);
  r[4] = f2bf(b[0]); r[5] = f2bf(b[1]); r[6] = f2bf(b[2]); r[7] = f2bf(b[3]);
  *(u16x8*)(xb + base) = r;
}

// ---------------- async 16B global -> LDS -----------------------------------
__device__ __forceinline__ void async16(const u16* g, u16* l) {
  __builtin_amdgcn_global_load_lds(
      (const __attribute__((address_space(1))) void*)g,
      (__attribute__((address_space(3))) void*)l,
      16, 0, 0);
}

#define BAR()   __builtin_amdgcn_s_barrier()
#define SCB()   __builtin_amdgcn_sched_barrier(0)
#define LGKM0() do { asm volatile("s_waitcnt lgkmcnt(0)" ::: "memory"); SCB(); } while (0)
#define LGKM4() do { asm volatile("s_waitcnt lgkmcnt(4)" ::: "memory"); SCB(); } while (0)
#define VMC8()  asm volatile("s_waitcnt vmcnt(8)" ::: "memory")
#define VMC4()  asm volatile("s_waitcnt vmcnt(4)" ::: "memory")
#define VMC4S() do { asm volatile("s_waitcnt vmcnt(4)" ::: "memory"); SCB(); } while (0)
#define VMC2S() do { asm volatile("s_waitcnt vmcnt(2)" ::: "memory"); SCB(); } while (0)
#define VMC0S() do { asm volatile("s_waitcnt vmcnt(0)" ::: "memory"); SCB(); } while (0)

// ---------------- 256x256 bf16 GEMM, B in registers, 1 barrier/K-tile -------
// 512 threads = 8 waves (2 M-waves x 4 N-waves). BK=64.
// A: LDS dbuf 64 KiB, 16x32 subtiles, quad slot = (col>>3)^((row>>1)&3)
// (0 bank conflicts, verified r3). B: global->reg dwordx4 per wave (values
// byte-identical to the staged path). Per-tile vm issue order:
// [Ast h0 x2, Ast h1 x2, bf0 x4, bf1 x4] -> VMC4=bf0, VMC2=bf1, VMC4@p3=A.
__global__ __launch_bounds__(512, 2)
void gemm_bf16_kernel(const u16* __restrict__ A,   // [Mdim][Kdim] bf16
                      const u16* __restrict__ B,   // [Ndim][Kdim] bf16
                      const float* __restrict__ bias,
                      float* __restrict__ C) {
  __shared__ u16 AsF[32768];   // [buf][half][8192 elems] = 64 KiB

  const int t    = threadIdx.x;
  const int lane = t & 63;
  const int w    = t >> 6;      // wave 0..7
  const int wm   = w >> 2;      // 0..1  -> A rows wm*128..+127
  const int wn   = w & 3;       // 0..3  -> B rows wn*64..+63
  const int fr   = lane & 15;
  const int fq   = lane >> 4;
  const int cswz = (fr & 6) << 2;   // ((fr>>1)&3)*8

  // T1: XCD-aware block swizzle (512 blocks, 512%8==0)
  const int bid = blockIdx.x;
  const int swz = (bid & 7) * 64 + (bid >> 3);
  const int m0 = (swz >> 4) * 256;   // 32 M-tiles
  const int n0 = (swz & 15) * 256;   // 16 N-tiles

  // A staging geometry: chunk c = l*512 + w*64 + lane (16 B), LDS linear.
  const int c0   = w * 64 + lane;
  const int r16s = (c0 & 63) >> 2;
  const int srow = ((c0 >> 7) << 4) + r16s;          // 0..63
  const int scol = ((c0 >> 6) & 1) * 32 + (((c0 & 3) * 8) ^ ((r16s & 6) << 2));
  const int dsto = c0 * 8;                           // LDS elem offset
  // 4 rolling A-source pointers (h,L): rows srow + {0,64,128,192}
  const u16* pa0 = A + (size_t)(m0 + srow) * Kdim + scol;
  const u16* pa1 = pa0 + (size_t)64  * Kdim;
  const u16* pa2 = pa0 + (size_t)128 * Kdim;
  const u16* pa3 = pa0 + (size_t)192 * Kdim;

  // 4 rolling B pointers, one per ni: row n0 + wn*64 + ni*16 + fr, col fq*8.
  const u16* bp0 = B + (size_t)(n0 + wn * 64 +  0 + fr) * Kdim + fq * 8;
  const u16* bp1 = B + (size_t)(n0 + wn * 64 + 16 + fr) * Kdim + fq * 8;
  const u16* bp2 = B + (size_t)(n0 + wn * 64 + 32 + fr) * Kdim + fq * 8;
  const u16* bp3 = B + (size_t)(n0 + wn * 64 + 48 + fr) * Kdim + fq * 8;

  // A fragment read offsets (elements): (q*2+i)*2+kk subtile * 512
  const int aoff = wm * 8192 + fr * 32 + ((fq * 8) ^ cswz);

  f32x4 acc[8][4] = {};
  short8 bf[2][4];      // [kk][ni], kk-half refreshed in place at p3
  short8 afA[2][2];     // even-q A frags (q0, q2)
  short8 afB[2][2];     // odd-q  A frags (q1, q3)

  auto rdA_A = [&](int buf, int q) {
#pragma unroll
    for (int kk = 0; kk < 2; ++kk)
#pragma unroll
      for (int i = 0; i < 2; ++i)
        afA[kk][i] = *(const short8*)&AsF[buf * 16384 + aoff + ((q * 2 + i) * 2 + kk) * 512];
  };
  auto rdA_B = [&](int buf, int q) {
#pragma unroll
    for (int kk = 0; kk < 2; ++kk)
#pragma unroll
      for (int i = 0; i < 2; ++i)
        afB[kk][i] = *(const short8*)&AsF[buf * 16384 + aoff + ((q * 2 + i) * 2 + kk) * 512];
  };
  auto bfload0 = [&]() {   // kk=0 half: cols [0,32) of the K-step
    asm volatile("global_load_dwordx4 %0, %1, off" : "=v"(bf[0][0]) : "v"(bp0) : "memory");
    asm volatile("global_load_dwordx4 %0, %1, off" : "=v"(bf[0][1]) : "v"(bp1) : "memory");
    asm volatile("global_load_dwordx4 %0, %1, off" : "=v"(bf[0][2]) : "v"(bp2) : "memory");
    asm volatile("global_load_dwordx4 %0, %1, off" : "=v"(bf[0][3]) : "v"(bp3) : "memory");
  };
  auto bfload1 = [&]() {   // kk=1 half: cols [32,64) -> +64 bytes
    asm volatile("global_load_dwordx4 %0, %1, off offset:64" : "=v"(bf[1][0]) : "v"(bp0) : "memory");
    asm volatile("global_load_dwordx4 %0, %1, off offset:64" : "=v"(bf[1][1]) : "v"(bp1) : "memory");
    asm volatile("global_load_dwordx4 %0, %1, off offset:64" : "=v"(bf[1][2]) : "v"(bp2) : "memory");
    asm volatile("global_load_dwordx4 %0, %1, off offset:64" : "=v"(bf[1][3]) : "v"(bp3) : "memory");
  };
  auto mfmaE_kk = [&](int q, int kk) {
    __builtin_amdgcn_s_setprio(1);
#pragma unroll
    for (int i = 0; i < 2; ++i)
#pragma unroll
      for (int ni = 0; ni < 4; ++ni)
        acc[q * 2 + i][ni] = __builtin_amdgcn_mfma_f32_16x16x32_bf16(
            afA[kk][i], bf[kk][ni], acc[q * 2 + i][ni], 0, 0, 0);
    __builtin_amdgcn_s_setprio(0);
  };
  auto mfmaO_kk = [&](int q, int kk) {
    __builtin_amdgcn_s_setprio(1);
#pragma unroll
    for (int i = 0; i < 2; ++i)
#pragma unroll
      for (int ni = 0; ni < 4; ++ni)
        acc[q * 2 + i][ni] = __builtin_amdgcn_mfma_f32_16x16x32_bf16(
            afB[kk][i], bf[kk][ni], acc[q * 2 + i][ni], 0, 0, 0);
    __builtin_amdgcn_s_setprio(0);
  };

  // Tile T (BUF=T&1). Entry invariant: afA=q0 frags' reads in flight (4 ds);
  // vm outstanding = 8 = bf(T) kk0+kk1.
#define KT(BUF)                                                          \
  {                                                                      \
    /* p0 */                                                             \
    rdA_B((BUF), 1);                                                     \
    LGKM4();                  /* q0 afA done; q1 in flight */            \
    VMC4S();                  /* bf[0] ready */                          \
    mfmaE_kk(0, 0);                                                      \
    async16(pa0, &AsF[((BUF ^ 1) * 2 + 0) * 8192 + dsto]);               \
    async16(pa1, &AsF[((BUF ^ 1) * 2 + 0) * 8192 + 4096 + dsto]);        \
    VMC2S();                  /* bf[1] ready ([bf1 4, Ast 2]) */         \
    mfmaE_kk(0, 1);                                                      \
    /* p1 */                                                             \
    rdA_A((BUF), 2);                                                     \
    async16(pa2, &AsF[((BUF ^ 1) * 2 + 1) * 8192 + dsto]);               \
    async16(pa3, &AsF[((BUF ^ 1) * 2 + 1) * 8192 + 4096 + dsto]);        \
    LGKM4();                  /* q1 done */                              \
    mfmaO_kk(1, 0); mfmaO_kk(1, 1);                                      \
    /* p2 */                                                             \
    rdA_B((BUF), 3);                                                     \
    LGKM4();                  /* q2 done */                              \
    mfmaE_kk(2, 0); mfmaE_kk(2, 1);                                      \
    /* p3 */                                                             \
    LGKM0();                  /* q3 done */                              \
    mfmaO_kk(3, 0);                                                      \
    bfload0();                /* bf[0] <- bf(T+1) after last kk0 use */  \
    VMC4();                   /* A(T+1) landed ([Ast4,bf0 4] -> <=4) */  \
    BAR();                                                               \
    rdA_A((BUF) ^ 1, 0);      /* boundary: q0 of next buf */             \
    mfmaO_kk(3, 1);                                                      \
    bfload1();                /* bf[1] <- bf(T+1) after last kk1 use */  \
    pa0 += 64; pa1 += 64; pa2 += 64; pa3 += 64;                          \
    bp0 += 64; bp1 += 64; bp2 += 64; bp3 += 64;                          \
  }

  // Prologue: stage A(0) (4 loads) + bf(0) (8 loads); VMC8 -> A(0) landed,
  // bf(0) in flight (=8, matching the invariant); barrier; q0 boundary reads.
  async16(pa0, &AsF[0 * 8192 + dsto]);
  async16(pa1, &AsF[0 * 8192 + 4096 + dsto]);
  async16(pa2, &AsF[1 * 8192 + dsto]);
  async16(pa3, &AsF[1 * 8192 + 4096 + dsto]);
  bfload0();
  bfload1();
  pa0 += 64; pa1 += 64; pa2 += 64; pa3 += 64;
  bp0 += 64; bp1 += 64; bp2 += 64; bp3 += 64;
  VMC8();
  BAR();
  rdA_A(0, 0);

  for (int t2 = 0; t2 < 31; ++t2) {       // K-tiles 0..61
    KT(0);
    KT(1);
  }
  KT(0);                                   // tile 62 (stages A(63), bf(63))

  // Tile 63 (BUF=1): no staging, no bf refresh, no barrier.
  {
    rdA_B(1, 1);
    LGKM4();
    VMC4S();                  // bf[0](63) ready
    mfmaE_kk(0, 0);
    VMC0S();                  // bf[1](63) ready (nothing else in flight)
    mfmaE_kk(0, 1);
    rdA_A(1, 2);
    LGKM4();
    mfmaO_kk(1, 0); mfmaO_kk(1, 1);
    rdA_B(1, 3);
    LGKM4();
    mfmaE_kk(2, 0); mfmaE_kk(2, 1);
    LGKM0();
    mfmaO_kk(3, 0); mfmaO_kk(3, 1);
  }

  // Epilogue: C/D map col=lane&15, row=(lane>>4)*4+j  [m89]
  float bv[4];
#pragma unroll
  for (int ni = 0; ni < 4; ++ni)
    bv[ni] = bias[n0 + wn * 64 + ni * 16 + fr];

#pragma unroll
  for (int mi = 0; mi < 8; ++mi) {
#pragma unroll
    for (int j = 0; j < 4; ++j) {
      const int row = m0 + wm * 128 + mi * 16 + fq * 4 + j;
      float* cp = C + (size_t)row * Ndim + n0 + wn * 64 + fr;
#pragma unroll
      for (int ni = 0; ni < 4; ++ni)
        cp[ni * 16] = acc[mi][ni][j] + bv[ni];
    }
  }
#undef KT
}

extern "C" void kernel_launch(void* const* d_in, const int* in_sizes, int n_in,
                              void* d_out, int out_size, void* d_ws, size_t ws_size,
                              hipStream_t stream) {
  const float* x    = (const float*)d_in[0];   // [8192][4096] fp32
  const float* cent = (const float*)d_in[1];   // [256] fp32
  const float* bias = (const float*)d_in[2];   // [4096] fp32
  const int*   idx  = (const int*)d_in[3];     // [4096][4096] int
  float* out = (float*)d_out;                  // [8192][4096] fp32

  u16* wb = (u16*)d_ws;
  u16* xb = (u16*)((char*)d_ws + (size_t)Ndim * Kdim * sizeof(u16));

  decode_weight_kernel<<<(Ndim * Kdim) / (256 * 8), 256, 0, stream>>>(idx, cent, wb);
  cvt_x_kernel<<<((size_t)Mdim * Kdim) / (256 * 8), 256, 0, stream>>>(x, xb);

  gemm_bf16_kernel<<<dim3(512), 512, 0, stream>>>(xb, wb, bias, out);
}

// Round 11
// 338.406 us; speedup vs baseline: 1.0237x; 1.0237x over previous
//
#include <hip/hip_runtime.h>
#include <hip/hip_bf16.h>
#include <stdint.h>

// out[m][n] = sum_k x[m][k] * centroids[idx[n][k]] + bias[n]
// M=8192, N=4096, K=4096. decode W->bf16, cvt x->bf16, then 256x256 MFMA GEMM.
// Round 10: r6 base, B moved out of LDS — per-wave B fragments loaded
// global->register via inline-asm global_load_dwordx4, kk-split double-buffer
// across the tile boundary. DS pipe (the measured bottleneck: ~2800 cyc/tile
// vs MFMA 2483) drops to ~1800 cyc/tile. A staging/LDS/swizzle unchanged.

typedef unsigned short u16;
typedef __attribute__((ext_vector_type(8))) short short8;   // bf16x8 (4 VGPR)
typedef __attribute__((ext_vector_type(8))) u16   u16x8;
typedef __attribute__((ext_vector_type(4))) float f32x4;
typedef __attribute__((ext_vector_type(4))) int   i32x4;

constexpr int Mdim = 8192;
constexpr int Ndim = 4096;
constexpr int Kdim = 4096;

__device__ __forceinline__ u16 f2bf(float f) {
  union { float f; uint32_t u; } v; v.f = f;
  uint32_t u = v.u;
  return (u16)((u + 0x7fffu + ((u >> 16) & 1u)) >> 16);
}

// ---------------- decode: weight_bf16[n*K + k] = bf16(cent[idx[n*K + k]]) ----
__global__ void decode_weight_kernel(const int* __restrict__ idx,
                                     const float* __restrict__ cent,
                                     u16* __restrict__ wb) {
  __shared__ u16 lut[256];
  const int t = threadIdx.x;
  if (t < 256) lut[t] = f2bf(cent[t]);
  __syncthreads();
  const size_t base = ((size_t)blockIdx.x * 256 + t) * 8;
  i32x4 i0 = *(const i32x4*)(idx + base);
  i32x4 i1 = *(const i32x4*)(idx + base + 4);
  u16x8 r;
  r[0] = lut[i0[0] & 255]; r[1] = lut[i0[1] & 255];
  r[2] = lut[i0[2] & 255]; r[3] = lut[i0[3] & 255];
  r[4] = lut[i1[0] & 255]; r[5] = lut[i1[1] & 255];
  r[6] = lut[i1[2] & 255]; r[7] = lut[i1[3] & 255];
  *(u16x8*)(wb + base) = r;
}

// ---------------- convert: x fp32 -> bf16 -----------------------------------
__global__ void cvt_x_kernel(const float* __restrict__ x, u16* __restrict__ xb) {
  const size_t base = ((size_t)blockIdx.x * 256 + threadIdx.x) * 8;
  f32x4 a = *(const f32x4*)(x + base);
  f32x4 b = *(const f32x4*)(x + base + 4);
  u16x8 r;
  r[0] = f2bf(a[0]); r[1] = f2bf(a[1]); r[2] = f2bf(a[2]); r[3] = f2bf(a[3]);
  r[4] = f2bf(b[0]); r[5] = f2bf(b[1]); r[6] = f2bf(b[2]); r[7] = f2bf(b[3]);
  *(u16x8*)(xb + base) = r;
}

// ---------------- async 16B global -> LDS -----------------------------------
__device__ __forceinline__ void async16(const u16* g, u16* l) {
  __builtin_amdgcn_global_load_lds(
      (const __attribute__((address_space(1))) void*)g,
      (__attribute__((address_space(3))) void*)l,
      16, 0, 0);
}

#define BAR()   __builtin_amdgcn_s_barrier()
#define SCB()   __builtin_amdgcn_sched_barrier(0)
#define LGKM0() do { asm volatile("s_waitcnt lgkmcnt(0)" ::: "memory"); SCB(); } while (0)
#define LGKM4() do { asm volatile("s_waitcnt lgkmcnt(4)" ::: "memory"); SCB(); } while (0)
#define VMC8()  asm volatile("s_waitcnt vmcnt(8)" ::: "memory")
#define VMC4()  asm volatile("s_waitcnt vmcnt(4)" ::: "memory")
#define VMC4S() do { asm volatile("s_waitcnt vmcnt(4)" ::: "memory"); SCB(); } while (0)
#define VMC2S() do { asm volatile("s_waitcnt vmcnt(2)" ::: "memory"); SCB(); } while (0)
#define VMC0S() do { asm volatile("s_waitcnt vmcnt(0)" ::: "memory"); SCB(); } while (0)

// ---------------- 256x256 bf16 GEMM, B in registers, 1 barrier/K-tile -------
// 512 threads = 8 waves (2 M-waves x 4 N-waves). BK=64.
// A: LDS dbuf 64 KiB, 16x32 subtiles, quad slot = (col>>3)^((row>>1)&3)
// (0 bank conflicts, verified r3). B: global->reg dwordx4 per wave (values
// byte-identical to the staged path). Per-tile vm issue order:
// [Ast h0 x2, Ast h1 x2, bf0 x4, bf1 x4] -> VMC4=bf0, VMC2=bf1, VMC4@p3=A.
__global__ __launch_bounds__(512, 2)
void gemm_bf16_kernel(const u16* __restrict__ A,   // [Mdim][Kdim] bf16
                      const u16* __restrict__ B,   // [Ndim][Kdim] bf16
                      const float* __restrict__ bias,
                      float* __restrict__ C) {
  __shared__ u16 AsF[32768];   // [buf][half][8192 elems] = 64 KiB

  const int t    = threadIdx.x;
  const int lane = t & 63;
  const int w    = t >> 6;      // wave 0..7
  const int wm   = w >> 2;      // 0..1  -> A rows wm*128..+127
  const int wn   = w & 3;       // 0..3  -> B rows wn*64..+63
  const int fr   = lane & 15;
  const int fq   = lane >> 4;
  const int cswz = (fr & 6) << 2;   // ((fr>>1)&3)*8

  // T1: XCD-aware block swizzle (512 blocks, 512%8==0)
  const int bid = blockIdx.x;
  const int swz = (bid & 7) * 64 + (bid >> 3);
  const int m0 = (swz >> 4) * 256;   // 32 M-tiles
  const int n0 = (swz & 15) * 256;   // 16 N-tiles

  // A staging geometry: chunk c = l*512 + w*64 + lane (16 B), LDS linear.
  const int c0   = w * 64 + lane;
  const int r16s = (c0 & 63) >> 2;
  const int srow = ((c0 >> 7) << 4) + r16s;          // 0..63
  const int scol = ((c0 >> 6) & 1) * 32 + (((c0 & 3) * 8) ^ ((r16s & 6) << 2));
  const int dsto = c0 * 8;                           // LDS elem offset
  // 4 rolling A-source pointers (h,L): rows srow + {0,64,128,192}
  const u16* pa0 = A + (size_t)(m0 + srow) * Kdim + scol;
  const u16* pa1 = pa0 + (size_t)64  * Kdim;
  const u16* pa2 = pa0 + (size_t)128 * Kdim;
  const u16* pa3 = pa0 + (size_t)192 * Kdim;

  // 4 rolling B pointers, one per ni: row n0 + wn*64 + ni*16 + fr, col fq*8.
  const u16* bp0 = B + (size_t)(n0 + wn * 64 +  0 + fr) * Kdim + fq * 8;
  const u16* bp1 = B + (size_t)(n0 + wn * 64 + 16 + fr) * Kdim + fq * 8;
  const u16* bp2 = B + (size_t)(n0 + wn * 64 + 32 + fr) * Kdim + fq * 8;
  const u16* bp3 = B + (size_t)(n0 + wn * 64 + 48 + fr) * Kdim + fq * 8;

  // A fragment read offsets (elements): (q*2+i)*2+kk subtile * 512
  const int aoff = wm * 8192 + fr * 32 + ((fq * 8) ^ cswz);

  f32x4 acc[8][4] = {};
  short8 bf[2][4];      // [kk][ni], kk-half refreshed in place at p3
  short8 afA[2][2];     // even-q A frags (q0, q2)
  short8 afB[2][2];     // odd-q  A frags (q1, q3)

  auto rdA_A = [&](int buf, int q) {
#pragma unroll
    for (int kk = 0; kk < 2; ++kk)
#pragma unroll
      for (int i = 0; i < 2; ++i)
        afA[kk][i] = *(const short8*)&AsF[buf * 16384 + aoff + ((q * 2 + i) * 2 + kk) * 512];
  };
  auto rdA_B = [&](int buf, int q) {
#pragma unroll
    for (int kk = 0; kk < 2; ++kk)
#pragma unroll
      for (int i = 0; i < 2; ++i)
        afB[kk][i] = *(const short8*)&AsF[buf * 16384 + aoff + ((q * 2 + i) * 2 + kk) * 512];
  };
  auto bfload0 = [&]() {   // kk=0 half: cols [0,32) of the K-step
    asm volatile("global_load_dwordx4 %0, %1, off" : "=v"(bf[0][0]) : "v"(bp0) : "memory");
    asm volatile("global_load_dwordx4 %0, %1, off" : "=v"(bf[0][1]) : "v"(bp1) : "memory");
    asm volatile("global_load_dwordx4 %0, %1, off" : "=v"(bf[0][2]) : "v"(bp2) : "memory");
    asm volatile("global_load_dwordx4 %0, %1, off" : "=v"(bf[0][3]) : "v"(bp3) : "memory");
  };
  auto bfload1 = [&]() {   // kk=1 half: cols [32,64) -> +64 bytes
    asm volatile("global_load_dwordx4 %0, %1, off offset:64" : "=v"(bf[1][0]) : "v"(bp0) : "memory");
    asm volatile("global_load_dwordx4 %0, %1, off offset:64" : "=v"(bf[1][1]) : "v"(bp1) : "memory");
    asm volatile("global_load_dwordx4 %0, %1, off offset:64" : "=v"(bf[1][2]) : "v"(bp2) : "memory");
    asm volatile("global_load_dwordx4 %0, %1, off offset:64" : "=v"(bf[1][3]) : "v"(bp3) : "memory");
  };
  auto mfmaE_kk = [&](int q, int kk) {
    __builtin_amdgcn_s_setprio(1);
#pragma unroll
    for (int i = 0; i < 2; ++i)
#pragma unroll
      for (int ni = 0; ni < 4; ++ni)
        acc[q * 2 + i][ni] = __builtin_amdgcn_mfma_f32_16x16x32_bf16(
            afA[kk][i], bf[kk][ni], acc[q * 2 + i][ni], 0, 0, 0);
    __builtin_amdgcn_s_setprio(0);
  };
  auto mfmaO_kk = [&](int q, int kk) {
    __builtin_amdgcn_s_setprio(1);
#pragma unroll
    for (int i = 0; i < 2; ++i)
#pragma unroll
      for (int ni = 0; ni < 4; ++ni)
        acc[q * 2 + i][ni] = __builtin_amdgcn_mfma_f32_16x16x32_bf16(
            afB[kk][i], bf[kk][ni], acc[q * 2 + i][ni], 0, 0, 0);
    __builtin_amdgcn_s_setprio(0);
  };

  // Tile T (BUF=T&1). Entry invariant: afA=q0 frags' reads in flight (4 ds);
  // vm outstanding = 8 = bf(T) kk0+kk1.
#define KT(BUF)                                                          \
  {                                                                      \
    /* p0 */                                                             \
    rdA_B((BUF), 1);                                                     \
    LGKM4();                  /* q0 afA done; q1 in flight */            \
    VMC4S();                  /* bf[0] ready */                          \
    mfmaE_kk(0, 0);                                                      \
    async16(pa0, &AsF[((BUF ^ 1) * 2 + 0) * 8192 + dsto]);               \
    async16(pa1, &AsF[((BUF ^ 1) * 2 + 0) * 8192 + 4096 + dsto]);        \
    VMC2S();                  /* bf[1] ready ([bf1 4, Ast 2]) */         \
    mfmaE_kk(0, 1);                                                      \
    /* p1 */                                                             \
    rdA_A((BUF), 2);                                                     \
    async16(pa2, &AsF[((BUF ^ 1) * 2 + 1) * 8192 + dsto]);               \
    async16(pa3, &AsF[((BUF ^ 1) * 2 + 1) * 8192 + 4096 + dsto]);        \
    LGKM4();                  /* q1 done */                              \
    mfmaO_kk(1, 0); mfmaO_kk(1, 1);                                      \
    /* p2 */                                                             \
    rdA_B((BUF), 3);                                                     \
    LGKM4();                  /* q2 done */                              \
    mfmaE_kk(2, 0); mfmaE_kk(2, 1);                                      \
    /* p3 */                                                             \
    LGKM0();                  /* q3 done */                              \
    mfmaO_kk(3, 0);                                                      \
    bfload0();                /* bf[0] <- bf(T+1) after last kk0 use */  \
    VMC4();                   /* A(T+1) landed ([Ast4,bf0 4] -> <=4) */  \
    BAR();                                                               \
    rdA_A((BUF) ^ 1, 0);      /* boundary: q0 of next buf */             \
    mfmaO_kk(3, 1);                                                      \
    bfload1();                /* bf[1] <- bf(T+1) after last kk1 use */  \
    pa0 += 64; pa1 += 64; pa2 += 64; pa3 += 64;                          \
    bp0 += 64; bp1 += 64; bp2 += 64; bp3 += 64;                          \
  }

  // Prologue: stage A(0) (4 loads) + bf(0) (8 loads); VMC8 -> A(0) landed,
  // bf(0) in flight (=8, matching the invariant); barrier; q0 boundary reads.
  async16(pa0, &AsF[0 * 8192 + dsto]);
  async16(pa1, &AsF[0 * 8192 + 4096 + dsto]);
  async16(pa2, &AsF[1 * 8192 + dsto]);
  async16(pa3, &AsF[1 * 8192 + 4096 + dsto]);
  bfload0();
  bfload1();
  pa0 += 64; pa1 += 64; pa2 += 64; pa3 += 64;
  bp0 += 64; bp1 += 64; bp2 += 64; bp3 += 64;
  VMC8();
  BAR();
  rdA_A(0, 0);

  for (int t2 = 0; t2 < 31; ++t2) {       // K-tiles 0..61
    KT(0);
    KT(1);
  }
  KT(0);                                   // tile 62 (stages A(63), bf(63))

  // Tile 63 (BUF=1): no staging, no bf refresh, no barrier.
  {
    rdA_B(1, 1);
    LGKM4();
    VMC4S();                  // bf[0](63) ready
    mfmaE_kk(0, 0);
    VMC0S();                  // bf[1](63) ready (nothing else in flight)
    mfmaE_kk(0, 1);
    rdA_A(1, 2);
    LGKM4();
    mfmaO_kk(1, 0); mfmaO_kk(1, 1);
    rdA_B(1, 3);
    LGKM4();
    mfmaE_kk(2, 0); mfmaE_kk(2, 1);
    LGKM0();
    mfmaO_kk(3, 0); mfmaO_kk(3, 1);
  }

  // Epilogue: C/D map col=lane&15, row=(lane>>4)*4+j  [m89]
  float bv[4];
#pragma unroll
  for (int ni = 0; ni < 4; ++ni)
    bv[ni] = bias[n0 + wn * 64 + ni * 16 + fr];

#pragma unroll
  for (int mi = 0; mi < 8; ++mi) {
#pragma unroll
    for (int j = 0; j < 4; ++j) {
      const int row = m0 + wm * 128 + mi * 16 + fq * 4 + j;
      float* cp = C + (size_t)row * Ndim + n0 + wn * 64 + fr;
#pragma unroll
      for (int ni = 0; ni < 4; ++ni)
        cp[ni * 16] = acc[mi][ni][j] + bv[ni];
    }
  }
#undef KT
}

extern "C" void kernel_launch(void* const* d_in, const int* in_sizes, int n_in,
                              void* d_out, int out_size, void* d_ws, size_t ws_size,
                              hipStream_t stream) {
  const float* x    = (const float*)d_in[0];   // [8192][4096] fp32
  const float* cent = (const float*)d_in[1];   // [256] fp32
  const float* bias = (const float*)d_in[2];   // [4096] fp32
  const int*   idx  = (const int*)d_in[3];     // [4096][4096] int
  float* out = (float*)d_out;                  // [8192][4096] fp32

  u16* wb = (u16*)d_ws;
  u16* xb = (u16*)((char*)d_ws + (size_t)Ndim * Kdim * sizeof(u16));

  decode_weight_kernel<<<(Ndim * Kdim) / (256 * 8), 256, 0, stream>>>(idx, cent, wb);
  cvt_x_kernel<<<((size_t)Mdim * Kdim) / (256 * 8), 256, 0, stream>>>(x, xb);

  gemm_bf16_kernel<<<dim3(512), 512, 0, stream>>>(xb, wb, bias, out);
}